// Round 6
// baseline (2133.094 us; speedup 1.0000x reference)
//
#include <hip/hip_runtime.h>

// GRU: B=256, T=2048, I=2, H=128. One workgroup (512 thr = 8 waves) per batch.
// R6 = R4's data layout + R5's DPP technique:
//   thread owns 6 rows x 16-col slice of W_hh (24 float4 in VGPRs).
//   Lane mapping in a 16-lane DPP row: q=(r16&3)|((r16>>1)&4) (slice 0..7),
//   jbit=(r16>>2)&1; reduce group = quads {Qk,Qk+2} -> quad_perm xor1, xor2,
//   row_ror:8 — three single-instruction v_add_f32_dpp (inline asm, s_nop 1
//   for the VALU->DPP hazard). h reads drop 64 -> 32 ds_read_b128 per step
//   (R5 was LDS-read-bound). Dots use packed v_pk_fma_f32.
// h double-buffered in LDS, 20-word slice stride (8 disjoint bank groups).
// One __syncthreads per step.

#define BB 256
#define TT 2048
#define HH 128
#define NT 512
#define SLW 20              // words per 16-float h slice (+4 pad)
#define HWORDS (8 * SLW)    // 160

typedef float v4f __attribute__((ext_vector_type(4)));
typedef float v2f __attribute__((ext_vector_type(2)));

#define LO2(v) __builtin_shufflevector((v), (v), 0, 1)
#define HI2(v) __builtin_shufflevector((v), (v), 2, 3)

// x += dpp_moved(x); s_nop 1 covers the VALU->DPP 2-wait-state hazard.
#define DPP_ADD(x, CTRLSTR) do { float _d;                                   \
    asm volatile("s_nop 1\n\t"                                               \
                 "v_add_f32_dpp %0, %1, %1 " CTRLSTR                         \
                 " row_mask:0xf bank_mask:0xf"                               \
                 : "=v"(_d) : "v"(x));                                       \
    (x) = _d; } while (0)

__device__ __forceinline__ float fast_sigmoid(float v) {
    return 1.0f / (1.0f + __expf(-v));
}
__device__ __forceinline__ float fast_tanh(float v) {
    v = fminf(fmaxf(v, -30.0f), 30.0f);
    float e = __expf(2.0f * v);
    return (e - 1.0f) / (e + 1.0f);
}

__global__ __launch_bounds__(NT, 2) void gru_seq_kernel(
    const float* __restrict__ x,        // [B, T, 2]
    const int*   __restrict__ lengths,  // [B]
    const float* __restrict__ W_ih,     // [384, 2]
    const float* __restrict__ W_hh,     // [384, 128]
    const float* __restrict__ b_ih,     // [384]
    const float* __restrict__ b_hh,     // [384]
    const float* __restrict__ head_w,   // [128]
    const float* __restrict__ head_b,   // [1]
    float* __restrict__ out)            // [B]
{
    __shared__ __align__(16) float x_lds[TT * 2];       // 16 KB
    __shared__ __align__(16) float h_lds[2][HWORDS];    // 1.25 KB
    __shared__ float red[64];

    const int tid = threadIdx.x;
    const int r16 = tid & 15;
    const int q   = (r16 & 3) | ((r16 >> 1) & 4);            // h slice 0..7
    const int j   = ((tid >> 4) << 1) | ((r16 >> 2) & 1);    // hidden pair 0..63
    const int b   = blockIdx.x;
    const int len = lengths[b];

    // --- weights: 6 rows (gate r,z,n x pair p) x 16-col slice ---
    v4f wv[24];
    #pragma unroll
    for (int rr = 0; rr < 6; ++rr) {
        const int gate = rr >> 1, p = rr & 1;
        const v4f* Wp = (const v4f*)(W_hh + (size_t)(gate * HH + 2 * j + p) * HH + 16 * q);
        #pragma unroll
        for (int c = 0; c < 4; ++c) wv[rr * 4 + c] = Wp[c];
    }

    // --- consumer (q==0) constants for hidden indices 2j, 2j+1 ---
    float2 wi_r[2] = {{0,0},{0,0}}, wi_z[2] = {{0,0},{0,0}}, wi_n[2] = {{0,0},{0,0}};
    float br[2] = {0,0}, bz[2] = {0,0}, bnn[2] = {0,0}, bhn[2] = {0,0}, hwv[2] = {0,0};
    if (q == 0) {
        #pragma unroll
        for (int p = 0; p < 2; ++p) {
            const int hj = 2 * j + p;
            wi_r[p] = ((const float2*)W_ih)[hj];
            wi_z[p] = ((const float2*)W_ih)[HH + hj];
            wi_n[p] = ((const float2*)W_ih)[2 * HH + hj];
            br[p]  = b_ih[hj] + b_hh[hj];
            bz[p]  = b_ih[HH + hj] + b_hh[HH + hj];
            bnn[p] = b_ih[2 * HH + hj];
            bhn[p] = b_hh[2 * HH + hj];
            hwv[p] = head_w[hj];
        }
    }

    // --- stage x[b] into LDS; zero both h buffers ---
    {
        const float4* xb4 = (const float4*)(x + (size_t)b * TT * 2);
        float4* xl4 = (float4*)x_lds;
        #pragma unroll
        for (int i = tid; i < TT * 2 / 4; i += NT) xl4[i] = xb4[i];
    }
    for (int i = tid; i < 2 * HWORDS; i += NT) ((float*)h_lds)[i] = 0.f;

    __syncthreads();

    float hreg0 = 0.f, hreg1 = 0.f;
    int buf = 0;
    const float2* x2 = (const float2*)x_lds;

    for (int t = 0; t < len; ++t) {
        const float2 xt = x2[t];

        const v4f* hb = (const v4f*)&h_lds[buf][SLW * q];
        const v4f hv0 = hb[0], hv1 = hb[1], hv2 = hb[2], hv3 = hb[3];
        const v2f h0l = LO2(hv0), h0h = HI2(hv0), h1l = LO2(hv1), h1h = HI2(hv1);
        const v2f h2l = LO2(hv2), h2h = HI2(hv2), h3l = LO2(hv3), h3h = HI2(hv3);

        float acc[6];
        #pragma unroll
        for (int rr = 0; rr < 6; ++rr) {
            const v4f w0 = wv[rr * 4], w1 = wv[rr * 4 + 1];
            const v4f w2 = wv[rr * 4 + 2], w3 = wv[rr * 4 + 3];
            v2f aA = {0.f, 0.f}, aB = {0.f, 0.f};
            aA = __builtin_elementwise_fma(LO2(w0), h0l, aA);
            aB = __builtin_elementwise_fma(HI2(w0), h0h, aB);
            aA = __builtin_elementwise_fma(LO2(w1), h1l, aA);
            aB = __builtin_elementwise_fma(HI2(w1), h1h, aB);
            aA = __builtin_elementwise_fma(LO2(w2), h2l, aA);
            aB = __builtin_elementwise_fma(HI2(w2), h2h, aB);
            aA = __builtin_elementwise_fma(LO2(w3), h3l, aA);
            aB = __builtin_elementwise_fma(HI2(w3), h3h, aB);
            acc[rr] = (aA.x + aA.y) + (aB.x + aB.y);
        }

        // 8-lane reduce over quads {Qk, Qk+2}: pure-VALU single-instr DPP
        #pragma unroll
        for (int rr = 0; rr < 6; ++rr) {
            DPP_ADD(acc[rr], "quad_perm:[1,0,3,2]");
            DPP_ADD(acc[rr], "quad_perm:[2,3,0,1]");
            DPP_ADD(acc[rr], "row_ror:8");
        }

        if (q == 0) {
            // p = 0 (hidden 2j)
            {
                const float rg = fast_sigmoid(fmaf(wi_r[0].x, xt.x, fmaf(wi_r[0].y, xt.y, br[0])) + acc[0]);
                const float zg = fast_sigmoid(fmaf(wi_z[0].x, xt.x, fmaf(wi_z[0].y, xt.y, bz[0])) + acc[2]);
                const float xn = fmaf(wi_n[0].x, xt.x, fmaf(wi_n[0].y, xt.y, bnn[0]));
                const float ng = fast_tanh(fmaf(rg, acc[4] + bhn[0], xn));
                hreg0 = ng + zg * (hreg0 - ng);
            }
            // p = 1 (hidden 2j+1)
            {
                const float rg = fast_sigmoid(fmaf(wi_r[1].x, xt.x, fmaf(wi_r[1].y, xt.y, br[1])) + acc[1]);
                const float zg = fast_sigmoid(fmaf(wi_z[1].x, xt.x, fmaf(wi_z[1].y, xt.y, bz[1])) + acc[3]);
                const float xn = fmaf(wi_n[1].x, xt.x, fmaf(wi_n[1].y, xt.y, bnn[1]));
                const float ng = fast_tanh(fmaf(rg, acc[5] + bhn[1], xn));
                hreg1 = ng + zg * (hreg1 - ng);
            }
            const int hi = 2 * j;    // even; hi, hi+1 in the same slice
            float* dst = &h_lds[buf ^ 1][SLW * (hi >> 4) + (hi & 15)];
            *(float2*)dst = make_float2(hreg0, hreg1);
        }
        __syncthreads();
        buf ^= 1;
    }

    // --- head: out[b] = dot(h, head_w) + head_b ---
    if (q == 0) red[j] = fmaf(hreg0, hwv[0], hreg1 * hwv[1]);
    __syncthreads();
    if (tid < 64) {
        float v = red[tid];
        #pragma unroll
        for (int off = 32; off > 0; off >>= 1) v += __shfl_xor(v, off, 64);
        if (tid == 0) out[b] = v + head_b[0];
    }
}

extern "C" void kernel_launch(void* const* d_in, const int* in_sizes, int n_in,
                              void* d_out, int out_size, void* d_ws, size_t ws_size,
                              hipStream_t stream) {
    const float* x      = (const float*)d_in[0];
    const int*   len    = (const int*)  d_in[1];
    const float* W_ih   = (const float*)d_in[2];
    const float* W_hh   = (const float*)d_in[3];
    const float* b_ih   = (const float*)d_in[4];
    const float* b_hh   = (const float*)d_in[5];
    const float* head_w = (const float*)d_in[6];
    const float* head_b = (const float*)d_in[7];
    float* out = (float*)d_out;

    gru_seq_kernel<<<BB, NT, 0, stream>>>(x, len, W_ih, W_hh, b_ih, b_hh,
                                          head_w, head_b, out);
}

// Round 7
// 1315.170 us; speedup vs baseline: 1.6219x; 1.6219x over previous
//
#include <hip/hip_runtime.h>

// GRU: B=256, T=2048, I=2, H=128. One workgroup per batch element.
// R7: 256 threads (4 waves, 1/SIMD) + amdgpu_waves_per_eu(1,1) -> 512-VGPR
// budget so the 6 rows x 32 cols of W_hh per thread (192 floats) provably
// stay resident (R2..R6 all showed VGPR_Count 68-88: compiler re-loaded
// weights inside the loop; layout experiments proved LDS issue was not the
// binding constraint). Thread (q=tid&3, jp=tid>>2) owns gate rows
// {r,z,n} x {2jp, 2jp+1}, 32-col slice q. h in double-buffered LDS with
// R5's proven 40-word-slice broadcast layout. Quad reduce = 2 single-instr
// v_add_f32_dpp (xor1/xor2), interleaved across the 6 accumulators.
// After the butterfly all quad lanes hold the sums: lane q=0 updates hidden
// unit 2jp, lane q=1 updates 2jp+1 (halves the masked-gate stretch).
// One __syncthreads per step.

#define BB 256
#define TT 2048
#define HH 128
#define NT 256
#define HWORDS 160   // 4 slices x 40 words (32 data + 8 pad)

typedef float v4f __attribute__((ext_vector_type(4)));
typedef float v2f __attribute__((ext_vector_type(2)));

#define LO2(v) __builtin_shufflevector((v), (v), 0, 1)
#define HI2(v) __builtin_shufflevector((v), (v), 2, 3)

#define PIN(v) asm volatile("" : "+v"(v))
#define PIN4(f) do { PIN((f).x); PIN((f).y); PIN((f).z); PIN((f).w); } while (0)

// x += quad_perm(x); s_nop 1 covers the VALU->DPP 2-wait-state hazard.
#define DPP_ADD_Q(x, QPSTR) do { float _d;                                   \
    asm volatile("s_nop 1\n\t"                                               \
                 "v_add_f32_dpp %0, %1, %1 " QPSTR                           \
                 " row_mask:0xf bank_mask:0xf"                               \
                 : "=v"(_d) : "v"(x));                                       \
    (x) = _d; } while (0)

__device__ __forceinline__ float fast_sigmoid(float v) {
    return 1.0f / (1.0f + __expf(-v));
}
__device__ __forceinline__ float fast_tanh(float v) {
    v = fminf(fmaxf(v, -30.0f), 30.0f);
    float e = __expf(2.0f * v);
    return (e - 1.0f) / (e + 1.0f);
}

__global__ __launch_bounds__(NT)
__attribute__((amdgpu_waves_per_eu(1, 1)))
void gru_seq_kernel(
    const float* __restrict__ x,        // [B, T, 2]
    const int*   __restrict__ lengths,  // [B]
    const float* __restrict__ W_ih,     // [384, 2]
    const float* __restrict__ W_hh,     // [384, 128]
    const float* __restrict__ b_ih,     // [384]
    const float* __restrict__ b_hh,     // [384]
    const float* __restrict__ head_w,   // [128]
    const float* __restrict__ head_b,   // [1]
    float* __restrict__ out)            // [B]
{
    __shared__ __align__(16) float x_lds[TT * 2];        // 16 KB
    __shared__ __align__(16) float h_lds[2][HWORDS];     // 1.25 KB
    __shared__ float red[HH];

    const int tid = threadIdx.x;
    const int q  = tid & 3;          // 32-col slice
    const int jp = tid >> 2;         // hidden pair index 0..63
    const int b  = blockIdx.x;
    const int len = lengths[b];

    // --- weights: 6 rows (gate g x pair p) x 32-col slice q -> 48 v4f ---
    v4f wv[6][8];
    #pragma unroll
    for (int g = 0; g < 3; ++g) {
        #pragma unroll
        for (int p = 0; p < 2; ++p) {
            const v4f* Wp = (const v4f*)(W_hh + (size_t)(g * HH + 2 * jp + p) * HH + 32 * q);
            #pragma unroll
            for (int c = 0; c < 8; ++c) wv[g * 2 + p][c] = Wp[c];
        }
    }
    #pragma unroll
    for (int rr = 0; rr < 6; ++rr)
        #pragma unroll
        for (int c = 0; c < 8; ++c) PIN4(wv[rr][c]);

    // --- consumer (q<2) constants for hidden unit hi = 2*jp + q ---
    const int hi = 2 * jp + q;
    float2 wir = {0, 0}, wiz = {0, 0}, win = {0, 0};
    float br = 0.f, bz = 0.f, bnn = 0.f, bhn = 0.f, hw = 0.f;
    if (q < 2) {
        wir = ((const float2*)W_ih)[hi];
        wiz = ((const float2*)W_ih)[HH + hi];
        win = ((const float2*)W_ih)[2 * HH + hi];
        br  = b_ih[hi] + b_hh[hi];
        bz  = b_ih[HH + hi] + b_hh[HH + hi];
        bnn = b_ih[2 * HH + hi];
        bhn = b_hh[2 * HH + hi];
        hw  = head_w[hi];
    }

    // --- stage x[b] into LDS; zero both h buffers ---
    {
        const float4* xb4 = (const float4*)(x + (size_t)b * TT * 2);
        float4* xl4 = (float4*)x_lds;
        #pragma unroll
        for (int i = tid; i < TT * 2 / 4; i += NT) xl4[i] = xb4[i];
    }
    for (int i = tid; i < 2 * HWORDS; i += NT) ((float*)h_lds)[i] = 0.f;

    __syncthreads();

    float hreg = 0.0f;   // h[hi] held by q<2 lanes
    int buf = 0;
    const float2* x2 = (const float2*)x_lds;

    for (int t = 0; t < len; ++t) {
        const float2 xt = x2[t];

        // h slice q: 8 x ds_read_b128, 4 distinct addrs/wave (broadcast,
        // banks disjoint across q: word 40q+4i)
        const v4f* hb = (const v4f*)&h_lds[buf][40 * q];
        v4f hv[8];
        #pragma unroll
        for (int i = 0; i < 8; ++i) hv[i] = hb[i];

        // 6 dot products, packed v_pk_fma_f32, 2 accumulators each
        float acc[6];
        #pragma unroll
        for (int rr = 0; rr < 6; ++rr) {
            v2f aA = {0.f, 0.f}, aB = {0.f, 0.f};
            #pragma unroll
            for (int i = 0; i < 8; ++i) {
                aA = __builtin_elementwise_fma(LO2(wv[rr][i]), LO2(hv[i]), aA);
                aB = __builtin_elementwise_fma(HI2(wv[rr][i]), HI2(hv[i]), aB);
            }
            acc[rr] = (aA.x + aA.y) + (aB.x + aB.y);
        }

        // quad butterfly (all 4 lanes end with the full sum); interleaved
        // across accs so no back-to-back same-register DPP dependency
        DPP_ADD_Q(acc[0], "quad_perm:[1,0,3,2]");
        DPP_ADD_Q(acc[1], "quad_perm:[1,0,3,2]");
        DPP_ADD_Q(acc[2], "quad_perm:[1,0,3,2]");
        DPP_ADD_Q(acc[3], "quad_perm:[1,0,3,2]");
        DPP_ADD_Q(acc[4], "quad_perm:[1,0,3,2]");
        DPP_ADD_Q(acc[5], "quad_perm:[1,0,3,2]");
        DPP_ADD_Q(acc[0], "quad_perm:[2,3,0,1]");
        DPP_ADD_Q(acc[1], "quad_perm:[2,3,0,1]");
        DPP_ADD_Q(acc[2], "quad_perm:[2,3,0,1]");
        DPP_ADD_Q(acc[3], "quad_perm:[2,3,0,1]");
        DPP_ADD_Q(acc[4], "quad_perm:[2,3,0,1]");
        DPP_ADD_Q(acc[5], "quad_perm:[2,3,0,1]");

        if (q < 2) {
            // lane q handles pair element p = q  (acc[g*2+q])
            const float rg = fast_sigmoid(fmaf(wir.x, xt.x, fmaf(wir.y, xt.y, br)) + acc[q]);
            const float zg = fast_sigmoid(fmaf(wiz.x, xt.x, fmaf(wiz.y, xt.y, bz)) + acc[2 + q]);
            const float xn = fmaf(win.x, xt.x, fmaf(win.y, xt.y, bnn));
            const float ng = fast_tanh(fmaf(rg, acc[4 + q] + bhn, xn));
            hreg = ng + zg * (hreg - ng);
            h_lds[buf ^ 1][40 * (hi >> 5) + (hi & 31)] = hreg;
        }
        __syncthreads();
        buf ^= 1;
    }

    // --- head: out[b] = dot(h, head_w) + head_b ---
    if (q < 2) red[hi] = hreg * hw;
    __syncthreads();
    if (tid < 64) {
        float v = red[tid] + red[tid + 64];
        #pragma unroll
        for (int off = 32; off > 0; off >>= 1) v += __shfl_xor(v, off, 64);
        if (tid == 0) out[b] = v + head_b[0];
    }
}

extern "C" void kernel_launch(void* const* d_in, const int* in_sizes, int n_in,
                              void* d_out, int out_size, void* d_ws, size_t ws_size,
                              hipStream_t stream) {
    const float* x      = (const float*)d_in[0];
    const int*   len    = (const int*)  d_in[1];
    const float* W_ih   = (const float*)d_in[2];
    const float* W_hh   = (const float*)d_in[3];
    const float* b_ih   = (const float*)d_in[4];
    const float* b_hh   = (const float*)d_in[5];
    const float* head_w = (const float*)d_in[6];
    const float* head_b = (const float*)d_in[7];
    float* out = (float*)d_out;

    gru_seq_kernel<<<BB, NT, 0, stream>>>(x, len, W_ih, W_hh, b_ih, b_hh,
                                          head_w, head_b, out);
}

// Round 8
// 1310.113 us; speedup vs baseline: 1.6282x; 1.0039x over previous
//
#include <hip/hip_runtime.h>

// GRU: B=256, T=2048, I=2, H=128. One workgroup (512 thr = 8 waves) per batch.
// R8 = R5 (best: 1306 us) + weight arch-VGPR residency forcing:
//   - amdgpu_num_vgpr(240) + waves_per_eu(2,2): explicit register budget.
//   - LDS padded to ~83 KB: the allocator's occupancy heuristic derives its
//     VGPR budget from LDS-permitted blocks/CU (17.9KB -> 8 blocks -> 128-reg
//     budget -> AGPR-spill of weights + per-use v_accvgpr_read copies, ~200
//     cyc/step of VALU in R5). 83KB -> 1 block/CU -> 256-reg budget. Grid is
//     256 blocks on 256 CUs, so >1 block/CU never happens anyway.
//   - DPP adds interleaved acc-major (no back-to-back same-reg DPP dep).
// Structure unchanged from R5: thread (q=tid&3, j=tid>>2) owns q-th 32-col
// slice of gate rows {j, 128+j, 256+j}; h double-buffered in LDS (40-word
// slice stride, conflict-free quad-broadcast reads); quad butterfly via
// single-instruction v_add_f32_dpp; packed v_pk_fma_f32 dots; 1 barrier/step.

#define BB 256
#define TT 2048
#define HH 128
#define NT 512
#define HWORDS 160   // 4 slices x 40 words (32 data + 8 pad)

typedef float v4f __attribute__((ext_vector_type(4)));
typedef float v2f __attribute__((ext_vector_type(2)));

#define LO2(v) __builtin_shufflevector((v), (v), 0, 1)
#define HI2(v) __builtin_shufflevector((v), (v), 2, 3)

// x += quad_perm(x); s_nop 1 covers the VALU->DPP 2-wait-state hazard
#define DPP_ADD_Q(x, QPSTR) do { float _d;                                   \
    asm volatile("s_nop 1\n\t"                                               \
                 "v_add_f32_dpp %0, %1, %1 " QPSTR                           \
                 " row_mask:0xf bank_mask:0xf"                               \
                 : "=v"(_d) : "v"(x));                                       \
    (x) = _d; } while (0)

__device__ __forceinline__ float fast_sigmoid(float v) {
    return 1.0f / (1.0f + __expf(-v));
}
__device__ __forceinline__ float fast_tanh(float v) {
    v = fminf(fmaxf(v, -30.0f), 30.0f);
    float e = __expf(2.0f * v);
    return (e - 1.0f) / (e + 1.0f);
}

__global__ __launch_bounds__(NT)
__attribute__((amdgpu_waves_per_eu(2, 2), amdgpu_num_vgpr(240)))
void gru_seq_kernel(
    const float* __restrict__ x,        // [B, T, 2]
    const int*   __restrict__ lengths,  // [B]
    const float* __restrict__ W_ih,     // [384, 2]
    const float* __restrict__ W_hh,     // [384, 128]
    const float* __restrict__ b_ih,     // [384]
    const float* __restrict__ b_hh,     // [384]
    const float* __restrict__ head_w,   // [128]
    const float* __restrict__ head_b,   // [1]
    float* __restrict__ out)            // [B]
{
    __shared__ __align__(16) float x_lds[TT * 2];        // 16 KB
    __shared__ __align__(16) float h_lds[2][HWORDS];     // 1.25 KB
    __shared__ float red[8];
    // Occupancy-heuristic pad: forces "1 block/CU" into the compiler's VGPR
    // budget calc. Never actually written (lengths >= 1).
    __shared__ float lds_pad[16384];                     // 64 KB

    const int tid = threadIdx.x;
    const int q = tid & 3;          // 32-col slice
    const int j = tid >> 2;         // hidden index 0..127
    const int b = blockIdx.x;
    const int len = lengths[b];
    if (len < 0) lds_pad[tid] = 0.f;   // keep pad live; never executes

    // --- weights for this thread's 3 row-slices (24 v4f = 96 floats) ---
    v4f wr[8], wz[8], wn[8];
    {
        const v4f* Wr = (const v4f*)(W_hh + (size_t)j * HH + q * 32);
        const v4f* Wz = (const v4f*)(W_hh + (size_t)(HH + j) * HH + q * 32);
        const v4f* Wn = (const v4f*)(W_hh + (size_t)(2 * HH + j) * HH + q * 32);
        #pragma unroll
        for (int i = 0; i < 8; ++i) { wr[i] = Wr[i]; wz[i] = Wz[i]; wn[i] = Wn[i]; }
    }

    // per-j scalar params (only q==0 lane uses them)
    float wir0 = 0.f, wir1 = 0.f, bir = 0.f;
    float wiz0 = 0.f, wiz1 = 0.f, biz = 0.f;
    float win0 = 0.f, win1 = 0.f, bin = 0.f;
    float bhr = 0.f, bhz = 0.f, bhn = 0.f, hw = 0.f;
    if (q == 0) {
        wir0 = W_ih[j * 2];            wir1 = W_ih[j * 2 + 1];            bir = b_ih[j];
        wiz0 = W_ih[(HH + j) * 2];     wiz1 = W_ih[(HH + j) * 2 + 1];     biz = b_ih[HH + j];
        win0 = W_ih[(2 * HH + j) * 2]; win1 = W_ih[(2 * HH + j) * 2 + 1]; bin = b_ih[2 * HH + j];
        bhr = b_hh[j]; bhz = b_hh[HH + j]; bhn = b_hh[2 * HH + j];
        hw = head_w[j];
    }

    // --- stage x[b] into LDS (float4, coalesced) ---
    {
        const float4* xb4 = (const float4*)(x + (size_t)b * TT * 2);
        float4* xl4 = (float4*)x_lds;
        #pragma unroll
        for (int i = tid; i < TT * 2 / 4; i += NT) xl4[i] = xb4[i];
    }
    // zero both h buffers
    for (int i = tid; i < 2 * HWORDS; i += NT) ((float*)h_lds)[i] = 0.f;

    __syncthreads();

    float h_reg = 0.0f;   // h[j] held by q==0 lanes
    int buf = 0;
    const float2* x2 = (const float2*)x_lds;

    for (int t = 0; t < len; ++t) {
        const float2 xt = x2[t];
        const float x0 = xt.x, x1 = xt.y;

        // read this thread's h slice (broadcast within quad, banks disjoint across q)
        const v4f* hb = (const v4f*)&h_lds[buf][40 * q];
        v4f hv[8];
        #pragma unroll
        for (int i = 0; i < 8; ++i) hv[i] = hb[i];

        // packed-fp32 dot products: 2 v2f accumulators per gate
        v2f arA = {0.f, 0.f}, arB = {0.f, 0.f};
        v2f azA = {0.f, 0.f}, azB = {0.f, 0.f};
        v2f anA = {0.f, 0.f}, anB = {0.f, 0.f};
        #pragma unroll
        for (int i = 0; i < 8; ++i) {
            const v2f hl = LO2(hv[i]), hh = HI2(hv[i]);
            arA = __builtin_elementwise_fma(LO2(wr[i]), hl, arA);
            arB = __builtin_elementwise_fma(HI2(wr[i]), hh, arB);
            azA = __builtin_elementwise_fma(LO2(wz[i]), hl, azA);
            azB = __builtin_elementwise_fma(HI2(wz[i]), hh, azB);
            anA = __builtin_elementwise_fma(LO2(wn[i]), hl, anA);
            anB = __builtin_elementwise_fma(HI2(wn[i]), hh, anB);
        }
        float ar = (arA.x + arA.y) + (arB.x + arB.y);
        float az = (azA.x + azA.y) + (azB.x + azB.y);
        float an = (anA.x + anA.y) + (anB.x + anB.y);

        // quad butterfly, acc-major interleave (no same-reg back-to-back DPP)
        DPP_ADD_Q(ar, "quad_perm:[1,0,3,2]");
        DPP_ADD_Q(az, "quad_perm:[1,0,3,2]");
        DPP_ADD_Q(an, "quad_perm:[1,0,3,2]");
        DPP_ADD_Q(ar, "quad_perm:[2,3,0,1]");
        DPP_ADD_Q(az, "quad_perm:[2,3,0,1]");
        DPP_ADD_Q(an, "quad_perm:[2,3,0,1]");

        if (q == 0) {
            const float r  = fast_sigmoid(fmaf(wir0, x0, fmaf(wir1, x1, bir)) + ar + bhr);
            const float z  = fast_sigmoid(fmaf(wiz0, x0, fmaf(wiz1, x1, biz)) + az + bhz);
            const float hn = an + bhn;
            const float xn = fmaf(win0, x0, fmaf(win1, x1, bin));
            const float n  = fast_tanh(fmaf(r, hn, xn));
            h_reg = n + z * (h_reg - n);
            h_lds[buf ^ 1][40 * (j >> 5) + (j & 31)] = h_reg;
        }
        __syncthreads();
        buf ^= 1;
    }

    // --- head: out[b] = dot(h, head_w) + head_b ---
    float p = (q == 0) ? h_reg * hw : 0.0f;
    #pragma unroll
    for (int off = 32; off > 0; off >>= 1) p += __shfl_xor(p, off);
    const int wid = tid >> 6;
    if ((tid & 63) == 0) red[wid] = p;
    __syncthreads();
    if (tid == 0) {
        float s = red[0];
        #pragma unroll
        for (int i = 1; i < 8; ++i) s += red[i];
        out[b] = s + head_b[0];
    }
}

extern "C" void kernel_launch(void* const* d_in, const int* in_sizes, int n_in,
                              void* d_out, int out_size, void* d_ws, size_t ws_size,
                              hipStream_t stream) {
    const float* x      = (const float*)d_in[0];
    const int*   len    = (const int*)  d_in[1];
    const float* W_ih   = (const float*)d_in[2];
    const float* W_hh   = (const float*)d_in[3];
    const float* b_ih   = (const float*)d_in[4];
    const float* b_hh   = (const float*)d_in[5];
    const float* head_w = (const float*)d_in[6];
    const float* head_b = (const float*)d_in[7];
    float* out = (float*)d_out;

    gru_seq_kernel<<<BB, NT, 0, stream>>>(x, len, W_ih, W_hh, b_ih, b_hh,
                                          head_w, head_b, out);
}

// Round 9
// 1068.882 us; speedup vs baseline: 1.9956x; 1.2257x over previous
//
#include <hip/hip_runtime.h>

// GRU: B=256, T=2048, I=2, H=128. One workgroup (512 thr = 8 waves) per batch.
// R9 = R5 (best family: 1306 us) + critical-path shavings:
//  (1) DPP butterfly asm made NON-volatile -> scheduler interleaves it with
//      the FMA tail (R4/R6 showed volatile-asm fences cost ~+1000 cyc/step
//      when multiplied; R5 pays 6 of them on the critical path).
//  (2) Gate transcendental chains shortened: weights/biases prescaled at
//      load (-log2e for r/z, 2*log2e for n) so gates are raw v_exp_f32 +
//      v_rcp_f32 with no extra muls and no clamps (inf limits exact).
//  (3) x-projections hoisted (computed from prefetched registers, off the
//      h-dependent path); x[t+1] prefetched during step t.
// Structure otherwise identical to R5: thread (q=tid&3, j=tid>>2) owns the
// q-th 32-col slice of gate rows {j, 128+j, 256+j}; h double-buffered in LDS
// (40-word slice stride, conflict-free quad-broadcast reads); packed
// v_pk_fma_f32 dots; quad butterfly v_add_f32_dpp; one barrier/step.

#define BB 256
#define TT 2048
#define HH 128
#define NT 512
#define HWORDS 160   // 4 slices x 40 words (32 data + 8 pad)

typedef float v4f __attribute__((ext_vector_type(4)));
typedef float v2f __attribute__((ext_vector_type(2)));

#define LO2(v) __builtin_shufflevector((v), (v), 0, 1)
#define HI2(v) __builtin_shufflevector((v), (v), 2, 3)

// d = dpp(x) + x in ONE v_add_f32_dpp; s_nop 1 covers the VALU->DPP
// 2-wait-state hazard. NON-volatile: pure function of x, schedulable.
#define DPP_ADD_Q(x, QPSTR) do { float _d;                                   \
    asm("s_nop 1\n\t"                                                        \
        "v_add_f32_dpp %0, %1, %1 " QPSTR " row_mask:0xf bank_mask:0xf"      \
        : "=v"(_d) : "v"(x));                                                \
    (x) = _d; } while (0)

__global__ __launch_bounds__(NT, 2) void gru_seq_kernel(
    const float* __restrict__ x,        // [B, T, 2]
    const int*   __restrict__ lengths,  // [B]
    const float* __restrict__ W_ih,     // [384, 2]
    const float* __restrict__ W_hh,     // [384, 128]
    const float* __restrict__ b_ih,     // [384]
    const float* __restrict__ b_hh,     // [384]
    const float* __restrict__ head_w,   // [128]
    const float* __restrict__ head_b,   // [1]
    float* __restrict__ out)            // [B]
{
    __shared__ __align__(16) float x_lds[(TT + 1) * 2];  // +1 slot: safe t+1 prefetch
    __shared__ __align__(16) float h_lds[2][HWORDS];
    __shared__ float red[8];

    const int tid = threadIdx.x;
    const int q = tid & 3;          // 32-col slice
    const int j = tid >> 2;         // hidden index 0..127
    const int b = blockIdx.x;
    const int len = lengths[b];

    const float S_RZ = -1.4426950408889634f;   // -log2(e)
    const float S_N  =  2.8853900817779268f;   //  2*log2(e)

    // --- weights for this thread's 3 row-slices, PRESCALED at load ---
    v4f wr[8], wz[8], wn[8];
    {
        const v4f* Wr = (const v4f*)(W_hh + (size_t)j * HH + q * 32);
        const v4f* Wz = (const v4f*)(W_hh + (size_t)(HH + j) * HH + q * 32);
        const v4f* Wn = (const v4f*)(W_hh + (size_t)(2 * HH + j) * HH + q * 32);
        #pragma unroll
        for (int i = 0; i < 8; ++i) {
            wr[i] = Wr[i] * S_RZ;
            wz[i] = Wz[i] * S_RZ;
            wn[i] = Wn[i] * S_N;
        }
    }

    // per-j scalar params (only q==0 lane uses them), prescaled
    float wir0 = 0.f, wir1 = 0.f, br = 0.f;
    float wiz0 = 0.f, wiz1 = 0.f, bz = 0.f;
    float win0 = 0.f, win1 = 0.f, bn = 0.f, bhn = 0.f, hw = 0.f;
    if (q == 0) {
        wir0 = S_RZ * W_ih[j * 2];            wir1 = S_RZ * W_ih[j * 2 + 1];
        br   = S_RZ * (b_ih[j] + b_hh[j]);
        wiz0 = S_RZ * W_ih[(HH + j) * 2];     wiz1 = S_RZ * W_ih[(HH + j) * 2 + 1];
        bz   = S_RZ * (b_ih[HH + j] + b_hh[HH + j]);
        win0 = S_N * W_ih[(2 * HH + j) * 2];  win1 = S_N * W_ih[(2 * HH + j) * 2 + 1];
        bn   = S_N * b_ih[2 * HH + j];
        bhn  = S_N * b_hh[2 * HH + j];
        hw   = head_w[j];
    }

    // --- stage x[b] into LDS (float4, coalesced) ---
    {
        const float4* xb4 = (const float4*)(x + (size_t)b * TT * 2);
        float4* xl4 = (float4*)x_lds;
        #pragma unroll
        for (int i = tid; i < TT * 2 / 4; i += NT) xl4[i] = xb4[i];
    }
    if (tid == 0) { x_lds[TT * 2] = 0.f; x_lds[TT * 2 + 1] = 0.f; }
    // zero both h buffers
    for (int i = tid; i < 2 * HWORDS; i += NT) ((float*)h_lds)[i] = 0.f;

    __syncthreads();

    float h_reg = 0.0f;   // h[j] held by q==0 lanes
    int buf = 0;
    const float2* x2 = (const float2*)x_lds;
    float2 xt = x2[0];    // x for step 0

    for (int t = 0; t < len; ++t) {
        // h slice reads (broadcast within quad, banks disjoint across q)
        const v4f* hb = (const v4f*)&h_lds[buf][40 * q];
        v4f hv[8];
        #pragma unroll
        for (int i = 0; i < 8; ++i) hv[i] = hb[i];

        // prefetch next x (independent; latency hidden behind FMAs)
        const float2 xt_next = x2[t + 1];

        // hoisted input projections (prescaled; independent of h reads)
        const float xpr = fmaf(wir0, xt.x, fmaf(wir1, xt.y, br));
        const float xpz = fmaf(wiz0, xt.x, fmaf(wiz1, xt.y, bz));
        const float xpn = fmaf(win0, xt.x, fmaf(win1, xt.y, bn));

        // packed-fp32 dot products: 2 v2f accumulators per gate
        v2f arA = {0.f, 0.f}, arB = {0.f, 0.f};
        v2f azA = {0.f, 0.f}, azB = {0.f, 0.f};
        v2f anA = {0.f, 0.f}, anB = {0.f, 0.f};
        #pragma unroll
        for (int i = 0; i < 8; ++i) {
            const v2f hl = LO2(hv[i]), hh = HI2(hv[i]);
            arA = __builtin_elementwise_fma(LO2(wr[i]), hl, arA);
            arB = __builtin_elementwise_fma(HI2(wr[i]), hh, arB);
            azA = __builtin_elementwise_fma(LO2(wz[i]), hl, azA);
            azB = __builtin_elementwise_fma(HI2(wz[i]), hh, azB);
            anA = __builtin_elementwise_fma(LO2(wn[i]), hl, anA);
            anB = __builtin_elementwise_fma(HI2(wn[i]), hh, anB);
        }
        float ar = (arA.x + arA.y) + (arB.x + arB.y);
        float az = (azA.x + azA.y) + (azB.x + azB.y);
        float an = (anA.x + anA.y) + (anB.x + anB.y);

        // quad butterfly, acc-major interleave, schedulable (non-volatile)
        DPP_ADD_Q(ar, "quad_perm:[1,0,3,2]");
        DPP_ADD_Q(az, "quad_perm:[1,0,3,2]");
        DPP_ADD_Q(an, "quad_perm:[1,0,3,2]");
        DPP_ADD_Q(ar, "quad_perm:[2,3,0,1]");
        DPP_ADD_Q(az, "quad_perm:[2,3,0,1]");
        DPP_ADD_Q(an, "quad_perm:[2,3,0,1]");

        if (q == 0) {
            // r = sigmoid(A) = rcp(1 + exp2(-log2e*A)); args prescaled
            const float r = __builtin_amdgcn_rcpf(1.f + __builtin_amdgcn_exp2f(ar + xpr));
            const float z = __builtin_amdgcn_rcpf(1.f + __builtin_amdgcn_exp2f(az + xpz));
            // n = tanh(A) = 1 - 2*rcp(1 + exp2(2*log2e*A)); inf limits exact
            const float u = __builtin_amdgcn_exp2f(fmaf(r, an + bhn, xpn));
            const float n = fmaf(-2.f, __builtin_amdgcn_rcpf(1.f + u), 1.f);
            h_reg = n + z * (h_reg - n);
            h_lds[buf ^ 1][40 * (j >> 5) + (j & 31)] = h_reg;
        }
        __syncthreads();
        buf ^= 1;
        xt = xt_next;
    }

    // --- head: out[b] = dot(h, head_w) + head_b ---
    float p = (q == 0) ? h_reg * hw : 0.0f;
    #pragma unroll
    for (int off = 32; off > 0; off >>= 1) p += __shfl_xor(p, off);
    const int wid = tid >> 6;
    if ((tid & 63) == 0) red[wid] = p;
    __syncthreads();
    if (tid == 0) {
        float s = red[0];
        #pragma unroll
        for (int i = 1; i < 8; ++i) s += red[i];
        out[b] = s + head_b[0];
    }
}

extern "C" void kernel_launch(void* const* d_in, const int* in_sizes, int n_in,
                              void* d_out, int out_size, void* d_ws, size_t ws_size,
                              hipStream_t stream) {
    const float* x      = (const float*)d_in[0];
    const int*   len    = (const int*)  d_in[1];
    const float* W_ih   = (const float*)d_in[2];
    const float* W_hh   = (const float*)d_in[3];
    const float* b_ih   = (const float*)d_in[4];
    const float* b_hh   = (const float*)d_in[5];
    const float* head_w = (const float*)d_in[6];
    const float* head_b = (const float*)d_in[7];
    float* out = (float*)d_out;

    gru_seq_kernel<<<BB, NT, 0, stream>>>(x, len, W_ih, W_hh, b_ih, b_hh,
                                          head_w, head_b, out);
}